// Round 13
// baseline (1444.270 us; speedup 1.0000x reference)
//
#include <hip/hip_runtime.h>

// out[n,k] = softmax_k( 2*x_n.c_k - ||c_k||^2 )   (x_sqr cancels in softmax)
// Round 13: EXACT 16-bit fixed-point i8 GEMM. Per-row scale F = 32639/max|v|,
// q = round(v*F) in [-32639,32639], q = 256*Qh + Ql (Qh,Ql int8).
// q_x.q_c = 65536*S_hh + 256*(S_hl+S_lh) + S_ll -- 4 i8 MFMA products
// (mfma_i32_16x16x64_i8, K=64, 2x bf16 OP rate, exact i32 accum), combined
// with ONE i32 acc + ONE f32 acc via progressive fold (fACC = 256*fACC + accP
// at product boundaries). 0.70x MFMA cycles and 0.67x LDS bytes vs the bf16
// 3-product path. Block 128x256, 8 waves of 64x64, BK=64(i8), 3-ring LDS
// 72 KiB, stage tt+2, counted vmcnt(3)+lgkm(0)+barrier per tile (r12 machinery),
// zero-conflict XOR swizzle (identical 64B-row structure, r7-verified).

typedef __attribute__((ext_vector_type(4))) int i32x4;
typedef __attribute__((ext_vector_type(4))) float f32x4;

typedef __attribute__((address_space(1))) const void global_cvoid;
typedef __attribute__((address_space(3))) void lds_void;

// ---------------- prep: quantize rows to split-i8, row scale, opt. row sq ----------------
template <int CB>
__global__ void quant_kernel(const float* __restrict__ in, char* __restrict__ hi,
                             char* __restrict__ lo, float* __restrict__ finv,
                             float* __restrict__ sqout) {
    int row = blockIdx.x * 4 + (threadIdx.x >> 6);
    int lane = threadIdx.x & 63;
    const float4* p = reinterpret_cast<const float4*>(in + (size_t)row * 512);
    float4 a = p[lane];
    float4 b = p[lane + 64];
    float va[8] = {a.x, a.y, a.z, a.w, b.x, b.y, b.z, b.w};
    float mx = 1e-20f, sq = 0.f;
#pragma unroll
    for (int j = 0; j < 8; ++j) {
        mx = fmaxf(mx, fabsf(va[j]));
        sq += va[j] * va[j];
    }
#pragma unroll
    for (int o = 32; o >= 1; o >>= 1) {
        mx = fmaxf(mx, __shfl_xor(mx, o));
        sq += __shfl_xor(sq, o);
    }
    float F = 32639.0f / mx;
    int qh[8], ql[8];
#pragma unroll
    for (int j = 0; j < 8; ++j) {
        float qf = fminf(fmaxf(va[j] * F, -32639.f), 32639.f);
        int q = (int)rintf(qf);
        int h = (q + 128) >> 8;          // in [-128,127]
        qh[j] = h;
        ql[j] = q - (h << 8);            // in [-128,127]
    }
    unsigned ph0 = (qh[0] & 255) | ((qh[1] & 255) << 8) | ((qh[2] & 255) << 16) | ((qh[3] & 255) << 24);
    unsigned ph1 = (qh[4] & 255) | ((qh[5] & 255) << 8) | ((qh[6] & 255) << 16) | ((qh[7] & 255) << 24);
    unsigned pl0 = (ql[0] & 255) | ((ql[1] & 255) << 8) | ((ql[2] & 255) << 16) | ((ql[3] & 255) << 24);
    unsigned pl1 = (ql[4] & 255) | ((ql[5] & 255) << 8) | ((ql[6] & 255) << 16) | ((ql[7] & 255) << 24);
    *(unsigned*)(hi + (size_t)row * 512 + lane * 4) = ph0;
    *(unsigned*)(hi + (size_t)row * 512 + (lane + 64) * 4) = ph1;
    *(unsigned*)(lo + (size_t)row * 512 + lane * 4) = pl0;
    *(unsigned*)(lo + (size_t)row * 512 + (lane + 64) * 4) = pl1;
    if (lane == 0) {
        finv[row] = mx * (1.0f / 32639.0f);
        if (CB) sqout[row] = sq;
    }
}

// ---------------- GEMM 128x256, i8 split, 4 products ----------------
// Grid 8192 (256 bm x 32 bn, bijective XCD swizzle), 512 threads = 8 waves
// (2 wm x 4 wn), each wave owns 64x64. LDS: A[3][128x64B] + B[3][256x64B]
// = 72 KiB. 32 tiles of BK=64 i8 (4 products x 8 chunks).
// Swizzle: 16B-slot col c_phys = c_log ^ ((row>>1)&3); row = 64 B = 4 slots
// (identical structure to the r7-verified zero-conflict layout).

#define RD_A(bq_)                                                                 \
    { _Pragma("unroll") for (int m = 0; m < 4; ++m)                               \
        afr[m] = *(const i32x4*)&ldsA[bq_][(a_slot + m * 64) * 16]; }

#define RD_B(bq_)                                                                 \
    { _Pragma("unroll") for (int n = 0; n < 4; ++n)                               \
        bfr[n] = *(const i32x4*)&ldsB[bq_][(b_slot + n * 64) * 16]; }

#define ST(tt_, bq_)                                                              \
    { int prod_ = (tt_) >> 3, ko_ = ((tt_) & 7) * 64;                             \
      const char* Asrc_ = (prod_ < 2 ? Xh : Xl) + arow0 + ko_;                    \
      const char* Bsrc_ = ((prod_ & 1) ? Cl : Ch) + brow0 + ko_;                  \
      __builtin_amdgcn_global_load_lds((global_cvoid*)(Asrc_ + goffA),            \
          (lds_void*)&ldsA[bq_][slA], 16, 0, 0);                                  \
      _Pragma("unroll") for (int j = 0; j < 2; ++j)                               \
          __builtin_amdgcn_global_load_lds((global_cvoid*)(Bsrc_ + goffB[j]),     \
              (lds_void*)&ldsB[bq_][slB[j]], 16, 0, 0);                           \
    }

#define MM_ALL()                                                                  \
    { _Pragma("unroll") for (int m = 0; m < 4; ++m)                               \
      _Pragma("unroll") for (int n = 0; n < 4; ++n)                               \
          accP[m][n] = __builtin_amdgcn_mfma_i32_16x16x64_i8(                     \
              afr[m], bfr[n], accP[m][n], 0, 0, 0); }

#define FOLD()                                                                    \
    { _Pragma("unroll") for (int m = 0; m < 4; ++m)                               \
      _Pragma("unroll") for (int n = 0; n < 4; ++n) {                             \
        _Pragma("unroll") for (int r = 0; r < 4; ++r)                             \
            fACC[m][n][r] = fACC[m][n][r] * 256.0f + (float)accP[m][n][r];        \
        accP[m][n] = (i32x4){0, 0, 0, 0};                                         \
      } }

template <int F16>
__global__ __launch_bounds__(512, 2) void gemm_kernel(
    const char* __restrict__ Xh, const char* __restrict__ Xl,
    const char* __restrict__ Ch, const char* __restrict__ Cl,
    const float* __restrict__ cbq, const float* __restrict__ fxinv,
    const float* __restrict__ fcinv, float* __restrict__ outf,
    unsigned short* __restrict__ p16, float* __restrict__ max_part,
    float* __restrict__ sum_part) {
    __shared__ __align__(16) char ldsA[3][8192];   // 24 KiB: [128 rows][64 B]
    __shared__ __align__(16) char ldsB[3][16384];  // 48 KiB: [256 rows][64 B]

    const int t = threadIdx.x;
    const int lane = t & 63;
    const int w = t >> 6;
    const int wm = w >> 2, wn = w & 3;  // 2 x 4 waves, each owns 64x64 output
    const int fr = lane & 15, fg = lane >> 4;

    int bid = blockIdx.x;
    int swz = (bid & 7) * 1024 + (bid >> 3);  // 8192 % 8 == 0 -> bijective
    const int bm = swz >> 5, bn = swz & 31;
    const int row0 = bm * 128, col0 = bn * 256;
    const size_t arow0 = (size_t)row0 * 512;  // bytes (i8 rows of 512)
    const size_t brow0 = (size_t)col0 * 512;

    const int xsl = fg ^ ((fr >> 1) & 3);
    const int a_slot = (wm * 64 + fr) * 4 + xsl;  // + m*64
    const int b_slot = (wn * 64 + fr) * 4 + xsl;  // + n*64

    // staging: phys slot s holds logical 16B-col (s&3)^(((s>>2)>>1)&3) of row s>>2
    int goffA, slA, goffB[2], slB[2];
    {
        int s = t, r_ = s >> 2, cp_ = s & 3;
        goffA = r_ * 512 + (cp_ ^ ((r_ >> 1) & 3)) * 16;
        slA = s * 16;
    }
#pragma unroll
    for (int j = 0; j < 2; ++j) {
        int s = j * 512 + t, r_ = s >> 2, cp_ = s & 3;
        goffB[j] = r_ * 512 + (cp_ ^ ((r_ >> 1) & 3)) * 16;
        slB[j] = s * 16;
    }

    i32x4 accP[4][4] = {};
    f32x4 fACC[4][4] = {};
    i32x4 afr[4], bfr[4];

    // prologue: stage tiles 0,1 into bufs 0,1 (6 loads); gate tile 0 (3 left)
    ST(0, 0);
    ST(1, 1);
    asm volatile("s_waitcnt vmcnt(3)\n\ts_barrier" ::: "memory");

    // 32 tiles: prod 0 = Xh.Ch (tiles 0-7), 1 = Xh.Cl (8-15), 2 = Xl.Ch (16-23),
    // 3 = Xl.Cl (24-31). Folds x256 after tiles 7 and 23 (S_hl,S_lh share weight).
    int bq = 0, sq = 2;
    for (int tt = 0; tt < 32; ++tt) {
        RD_B(bq);
        RD_A(bq);
        if (tt < 30) ST(tt + 2, sq);
        MM_ALL();  // compiler inserts fine-grained lgkmcnt before MFMA uses
        if (tt == 7 || tt == 23) FOLD();
        if (tt < 30) {
            asm volatile("s_waitcnt vmcnt(3) lgkmcnt(0)\n\ts_barrier" ::: "memory");
        } else if (tt == 30) {
            asm volatile("s_waitcnt vmcnt(0) lgkmcnt(0)\n\ts_barrier" ::: "memory");
        } else {
            asm volatile("s_waitcnt lgkmcnt(0)\n\ts_barrier" ::: "memory");
        }
        bq = (bq == 2) ? 0 : bq + 1;
        sq = (sq == 2) ? 0 : sq + 1;
    }
    FOLD();  // final: fACC = 65536*S_hh + 256*(S_hl+S_lh) + S_ll  (exact in q-space)

    // ---- epilogue: logits, softmax partials, store ----
    float* redm = (float*)&ldsA[0][0];  // [4 wn][128 rows]
    float* reds = redm + 512;

    float cq[4], fcv[4];
#pragma unroll
    for (int n = 0; n < 4; ++n) {
        int col = col0 + wn * 64 + n * 16 + fr;
        cq[n] = cbq[col];
        fcv[n] = fcinv[col];
    }
    float fxv[4][4];
#pragma unroll
    for (int m = 0; m < 4; ++m)
#pragma unroll
        for (int r = 0; r < 4; ++r)
            fxv[m][r] = fxinv[row0 + wm * 64 + m * 16 + fg * 4 + r];

    // logit = 2 * fxinv * fcinv * dot_q - cbq
#pragma unroll
    for (int m = 0; m < 4; ++m)
#pragma unroll
        for (int n = 0; n < 4; ++n)
#pragma unroll
            for (int r = 0; r < 4; ++r)
                fACC[m][n][r] = 2.0f * fxv[m][r] * fcv[n] * fACC[m][n][r] - cq[n];

    float rmx[4][4];
#pragma unroll
    for (int m = 0; m < 4; ++m)
#pragma unroll
        for (int r = 0; r < 4; ++r) {
            float v = fmaxf(fmaxf(fACC[m][0][r], fACC[m][1][r]),
                            fmaxf(fACC[m][2][r], fACC[m][3][r]));
#pragma unroll
            for (int o = 1; o < 16; o <<= 1) v = fmaxf(v, __shfl_xor(v, o));
            rmx[m][r] = v;
        }
    __syncthreads();  // all waves out of the K-loop before LDS reuse
    if (fr == 0) {
#pragma unroll
        for (int m = 0; m < 4; ++m)
#pragma unroll
            for (int r = 0; r < 4; ++r)
                redm[wn * 128 + wm * 64 + m * 16 + fg * 4 + r] = rmx[m][r];
    }
    __syncthreads();
#pragma unroll
    for (int m = 0; m < 4; ++m)
#pragma unroll
        for (int r = 0; r < 4; ++r) {
            int row = wm * 64 + m * 16 + fg * 4 + r;
            rmx[m][r] = fmaxf(fmaxf(redm[row], redm[128 + row]),
                              fmaxf(redm[256 + row], redm[384 + row]));
        }
#pragma unroll
    for (int m = 0; m < 4; ++m)
#pragma unroll
        for (int r = 0; r < 4; ++r) {
            float s = 0.f;
#pragma unroll
            for (int n = 0; n < 4; ++n) s += __expf(fACC[m][n][r] - rmx[m][r]);
#pragma unroll
            for (int o = 1; o < 16; o <<= 1) s += __shfl_xor(s, o);
            if (fr == 0) reds[wn * 128 + wm * 64 + m * 16 + fg * 4 + r] = s;
        }
    __syncthreads();
    if (wn == 0 && fr == 0) {
#pragma unroll
        for (int m = 0; m < 4; ++m)
#pragma unroll
            for (int r = 0; r < 4; ++r) {
                int row = wm * 64 + m * 16 + fg * 4 + r;
                size_t gr = (size_t)(row0 + row);
                max_part[gr * 32 + bn] = rmx[m][r];
                sum_part[gr * 32 + bn] =
                    reds[row] + reds[128 + row] + reds[256 + row] + reds[384 + row];
            }
    }
#pragma unroll
    for (int m = 0; m < 4; ++m)
#pragma unroll
        for (int n = 0; n < 4; ++n)
#pragma unroll
            for (int r = 0; r < 4; ++r) {
                size_t gr = (size_t)(row0 + wm * 64 + m * 16 + fg * 4 + r);
                size_t gi = gr * 8192 + col0 + wn * 64 + n * 16 + fr;
                if constexpr (F16) {
                    union { _Float16 h; unsigned short u; } cv;
                    cv.h = (_Float16)__expf(fACC[m][n][r] - rmx[m][r]);
                    p16[gi] = cv.u;
                } else {
                    outf[gi] = fACC[m][n][r];
                }
            }
}

// ---------------- combine partials over 32 col-blocks per row ----------------
__global__ void combine_kernel(const float* __restrict__ max_part,
                               const float* __restrict__ sum_part,
                               float* __restrict__ row_m, float* __restrict__ row_is,
                               float* __restrict__ scale, int do_scale) {
    int row = blockIdx.x * 8 + (threadIdx.x >> 5);
    int l = threadIdx.x & 31;
    size_t off = (size_t)row * 32 + l;
    float m = max_part[off];
    float s = sum_part[off];
    float gm = m;
#pragma unroll
    for (int o = 16; o >= 1; o >>= 1) gm = fmaxf(gm, __shfl_xor(gm, o, 32));
    float c = s * __expf(m - gm);
#pragma unroll
    for (int o = 16; o >= 1; o >>= 1) c += __shfl_xor(c, o, 32);
    float inv = 1.0f / c;
    if (do_scale) scale[off] = __expf(m - gm) * inv;
    if (l == 0) {
        row_m[row] = gm;
        row_is[row] = inv;
    }
}

// ---------------- normalize: f32-logit path ----------------
__global__ void norm_kernel(float* __restrict__ out, const float* __restrict__ row_m,
                            const float* __restrict__ row_is) {
    size_t i = (size_t)blockIdx.x * blockDim.x + threadIdx.x;
    size_t stride = (size_t)gridDim.x * blockDim.x;
    const size_t n4 = 268435456ull / 4;
    float4* p = reinterpret_cast<float4*>(out);
    for (; i < n4; i += stride) {
        int row = (int)(i >> 11);
        float m = row_m[row];
        float is = row_is[row];
        float4 v = p[i];
        v.x = __expf(v.x - m) * is;
        v.y = __expf(v.y - m) * is;
        v.z = __expf(v.z - m) * is;
        v.w = __expf(v.w - m) * is;
        p[i] = v;
    }
}

// ---------------- normalize: f16-exp path ----------------
__global__ void norm_f16_kernel(const unsigned short* __restrict__ p16,
                                const float* __restrict__ scale,
                                float* __restrict__ out) {
    size_t i = (size_t)blockIdx.x * blockDim.x + threadIdx.x;  // 8-elem group id
    size_t stride = (size_t)gridDim.x * blockDim.x;
    const size_t ng = 268435456ull / 8;
    const uint4* src = reinterpret_cast<const uint4*>(p16);
    float4* dst = reinterpret_cast<float4*>(out);
    for (; i < ng; i += stride) {
        int row = (int)(i >> 10);        // 1024 groups per row
        int bn = (int)((i >> 5) & 31);   // 32 groups per 256-col block
        float s = scale[(size_t)row * 32 + bn];
        union { uint4 u; _Float16 h[8]; } cv;
        cv.u = src[i];
        float4 o1, o2;
        o1.x = (float)cv.h[0] * s; o1.y = (float)cv.h[1] * s;
        o1.z = (float)cv.h[2] * s; o1.w = (float)cv.h[3] * s;
        o2.x = (float)cv.h[4] * s; o2.y = (float)cv.h[5] * s;
        o2.z = (float)cv.h[6] * s; o2.w = (float)cv.h[7] * s;
        dst[i * 2] = o1;
        dst[i * 2 + 1] = o2;
    }
}

extern "C" void kernel_launch(void* const* d_in, const int* in_sizes, int n_in,
                              void* d_out, int out_size, void* d_ws, size_t ws_size,
                              hipStream_t stream) {
    const float* x = (const float*)d_in[0];   // [32768,512]
    const float* cb = (const float*)d_in[1];  // [8192,512]
    float* out = (float*)d_out;               // [32768,8192]
    char* ws = (char*)d_ws;

    char* Xh        = ws;                                   // 16,777,216
    char* Xl        = ws + 16777216ull;                     // 16,777,216
    char* Ch        = ws + 33554432ull;                     //  4,194,304
    char* Cl        = ws + 37748736ull;                     //  4,194,304
    float* cbq      = (float*)(ws + 41943040ull);           //     32,768
    float* fxinv    = (float*)(ws + 41975808ull);           //    131,072
    float* fcinv    = (float*)(ws + 42106880ull);           //     32,768
    float* max_part = (float*)(ws + 42139648ull);           //  4,194,304
    float* sum_part = (float*)(ws + 46333952ull);           //  4,194,304
    float* row_m    = (float*)(ws + 50528256ull);           //    131,072
    float* row_is   = (float*)(ws + 50659328ull);           //    131,072
    float* scale    = (float*)(ws + 50790400ull);           //  4,194,304
    unsigned short* p16 = (unsigned short*)(ws + 54984704ull);  // 536,870,912 -> 591,855,616

    const bool f16path = (ws_size >= 591855616ull);

    quant_kernel<0><<<8192, 256, 0, stream>>>(x, Xh, Xl, fxinv, nullptr);
    quant_kernel<1><<<2048, 256, 0, stream>>>(cb, Ch, Cl, fcinv, cbq);
    if (f16path) {
        gemm_kernel<1><<<8192, 512, 0, stream>>>(Xh, Xl, Ch, Cl, cbq, fxinv, fcinv,
                                                 out, p16, max_part, sum_part);
        combine_kernel<<<4096, 256, 0, stream>>>(max_part, sum_part, row_m, row_is,
                                                 scale, 1);
        norm_f16_kernel<<<4096, 256, 0, stream>>>(p16, scale, out);
    } else {
        gemm_kernel<0><<<8192, 512, 0, stream>>>(Xh, Xl, Ch, Cl, cbq, fxinv, fcinv,
                                                 out, p16, max_part, sum_part);
        combine_kernel<<<4096, 256, 0, stream>>>(max_part, sum_part, row_m, row_is,
                                                 scale, 0);
        norm_kernel<<<4096, 256, 0, stream>>>(out, row_m, row_is);
    }
}